// Round 9
// baseline (116.221 us; speedup 1.0000x reference)
//
#include <hip/hip_runtime.h>
#include <cstdint>
#include <cstddef>

#define NB 512
#define NL 32
#define KD 512    // P*D
#define HKD 256   // k-half per pass

// swizzled float-offset of chunk ch (4 floats) of row `row` in a [32][256] pass buffer.
__device__ __forceinline__ int swz_off(int row, int ch) {
  int csw = (ch & ~15) | ((ch ^ (row >> 1)) & 15);
  return row * HKD + csw * 4;
}

__device__ __forceinline__ float readlane_f(float x, int lane) {
  return __int_as_float(__builtin_amdgcn_readlane(__float_as_int(x), lane));
}
__device__ __forceinline__ int readlane_i(int x, int lane) {
  return __builtin_amdgcn_readlane(x, lane);
}

template<int CTRL, int RM>
__device__ __forceinline__ float dppmin(float x) {
  int m = __builtin_amdgcn_update_dpp(__float_as_int(x), __float_as_int(x), CTRL, RM, 0xf, false);
  return fminf(x, __int_as_float(m));
}
// min over lanes 0..31, broadcast to all lanes via SGPR
__device__ __forceinline__ float wave_min32_bcast(float x) {
  x = dppmin<0xB1, 0xf>(x);   // quad_perm xor1
  x = dppmin<0x4E, 0xf>(x);   // quad_perm xor2
  x = dppmin<0x124, 0xf>(x);  // row_ror:4
  x = dppmin<0x128, 0xf>(x);  // row_ror:8 -> row16 min everywhere
  x = dppmin<0x142, 0xa>(x);  // row_bcast:15 -> lanes 16..31 = min(lanes 0..31)
  return readlane_f(x, 31);
}

// One fused kernel: cost (8-wave k-split) -> LDS reduce -> wave-0 hungarian ->
// last-block finalize. 512 blocks x 512 threads, 64 KB LDS -> 2 blk/CU, 4 waves/SIMD.
__global__ __launch_bounds__(512, 4)
void fused_kernel(const float* __restrict__ pred,
                  const float* __restrict__ prob,
                  const float* __restrict__ tgt,
                  const float* __restrict__ lmask,
                  const int* __restrict__ clf,
                  float* __restrict__ part,
                  unsigned int* __restrict__ counter,
                  float* __restrict__ out) {
  __shared__ float smem[16384];   // 64 KB: staging; aliased by partials + cost later
  const int b = blockIdx.x;
  const int tid = threadIdx.x;
  float* predH = smem;
  float* tgtH  = smem + 8192;

  const int w = tid >> 6, l = tid & 63;   // 8 waves, each owns a 32-float k-slice/pass
  const int ti = l >> 3, tj = l & 7;      // 8x8 lanes of 4x4 output tiles
  float acc[4][4];
#pragma unroll
  for (int a = 0; a < 4; ++a)
#pragma unroll
    for (int c2 = 0; c2 < 4; ++c2) acc[a][c2] = 0.f;

  for (int hp = 0; hp < 2; ++hp) {
    __syncthreads();
    const size_t base = (size_t)b * (NL * KD) + (size_t)hp * HKD;
#pragma unroll
    for (int it = 0; it < 4; ++it) {
      int chunk = tid + it * 512;          // 0..2047 -> row, chunk-in-row
      int row = chunk >> 6, ch = chunk & 63;
      const float4 pv = *reinterpret_cast<const float4*>(pred + base + (size_t)row * KD + ch * 4);
      const float4 tv = *reinterpret_cast<const float4*>(tgt  + base + (size_t)row * KD + ch * 4);
      int off = swz_off(row, ch);
      *reinterpret_cast<float4*>(predH + off) = pv;
      *reinterpret_cast<float4*>(tgtH  + off) = tv;
    }
    __syncthreads();
#pragma unroll
    for (int c0 = 0; c0 < 8; ++c0) {
      const int c = (w << 3) + c0;         // wave's 8 chunks of this pass
      float4 pr[4], tg[4];
#pragma unroll
      for (int r = 0; r < 4; ++r) {
        pr[r] = *reinterpret_cast<const float4*>(predH + swz_off(4 * ti + r, c));
        tg[r] = *reinterpret_cast<const float4*>(tgtH  + swz_off(4 * tj + r, c));
      }
#pragma unroll
      for (int a = 0; a < 4; ++a)
#pragma unroll
        for (int c2 = 0; c2 < 4; ++c2) {
          float d;
          d = pr[a].x - tg[c2].x; acc[a][c2] += d * d;
          d = pr[a].y - tg[c2].y; acc[a][c2] += d * d;
          d = pr[a].z - tg[c2].z; acc[a][c2] += d * d;
          d = pr[a].w - tg[c2].w; acc[a][c2] += d * d;
        }
    }
  }
  __syncthreads();   // all staging reads done; alias LDS: partials in [0..8192)
#pragma unroll
  for (int a = 0; a < 4; ++a) {
    float4 v = make_float4(acc[a][0], acc[a][1], acc[a][2], acc[a][3]);
    *reinterpret_cast<float4*>(&smem[w * 1024 + (4 * ti + a) * 32 + 4 * tj]) = v;
  }
  __syncthreads();
  {  // reduce 8 k-planes; cost -> smem[8192..9216) (old tgtH start, reads done)
    float2 s = make_float2(0.f, 0.f);
#pragma unroll
    for (int w2 = 0; w2 < 8; ++w2) {
      float2 p = *reinterpret_cast<const float2*>(&smem[w2 * 1024 + 2 * tid]);
      s.x += p.x; s.y += p.y;
    }
    *reinterpret_cast<float2*>(&smem[8192 + 2 * tid]) = s;
  }
  __syncthreads();

  if (tid >= 64) return;            // waves 1-7 exit; wave 0 runs the matching
  const float* cs = smem + 8192;    // cost[32][32]
  const int lane = tid;

  float lm = (lane < 32) ? lmask[b * 32 + lane] : 0.f;
  const int n = __popcll(__ballot(lm > 0.5f));
  float clfpart = 0.f;
  if (lane < 32 && lm > 0.5f) {
    int cc = clf[b * 32 + lane];
    clfpart = -logf(prob[(size_t)(b * 32 + lane) * 2 + cc]);
  }

  const float FINF = 1e30f;
  const bool activecol = (lane < n);
  const int cl = lane & 31;   // lanes 32..63 mirror -> same-addr broadcast (free)

  // Reference-faithful broken JV (minv/way never persisted in the python):
  // each step: fresh argmin over free cols of cost[i0][j]-u[i0]-v[j];
  // "augment" collapses to p[j_final] = ri. The uniform u[i0] doesn't affect
  // the argmin, so the min runs on key = c - v; delta = min(key) - u[i0].
  float u_r = 0.f, v_j = 0.f;
  int p_j = -1;

  for (int ri = 0; ri < n; ++ri) {
    int i0 = ri;
    bool usedc = false;
    bool usedr = (lane == ri);
    float rowv = cs[i0 * 32 + cl];
    while (true) {
      float key = rowv - v_j;                   // reduced cost (sans uniform u0)
      bool act = activecol && !usedc;
      float m = act ? key : FINF;
      float u0 = readlane_f(u_r, i0);           // off the min critical path
      float mn = wave_min32_bcast(m);
      uint64_t tie = __ballot(m == mn);
      int j1 = __ffsll((unsigned long long)tie) - 1;  // numpy first-index tie-break
      int pj1 = readlane_i(p_j, j1);
      int i0n = pj1 < 0 ? 0 : pj1;
      float rowv_n = cs[i0n * 32 + cl];         // speculative next-row read (pre-branch)
      float delta = mn - u0;
      if (usedr) u_r += delta;                  // u[p[used]] += delta
      if (usedc) v_j -= delta;                  // v[used]    -= delta
      if (pj1 < 0) {                            // free column -> p[j1] = ri, done
        if (lane == j1) p_j = ri;
        break;
      }
      usedc = usedc || (lane == j1);
      i0 = pj1;
      usedr = usedr || (lane == i0);
      rowv = rowv_n;
    }
  }

  // column j matched to row p[j] -> contributes cost[p[j]][j]
  int pj = p_j < 0 ? 0 : p_j;
  float a = activecol ? cs[pj * 32 + cl] : 0.f;
#pragma unroll
  for (int off = 32; off; off >>= 1) {
    a += __shfl_xor(a, off);
    clfpart += __shfl_xor(clfpart, off);
  }
  if (lane == 0) {
    part[b * 3 + 0] = a;
    part[b * 3 + 1] = clfpart;
    part[b * 3 + 2] = (float)n;
  }

  // ---- last-block finalize (device-scope release/acquire per G16) ----
  // counter is memset to 0 on the stream before this kernel each call, so the
  // TRUE last arrival (and only it) sees t == NB-1.  (R8 bug: with a poisoned
  // counter, (t & 511)==511 picked an EARLY arriver -> reduced poison.)
  __threadfence();                       // release part[b] writes
  unsigned int t = 0;
  if (lane == 0) t = atomicAdd(counter, 1u);
  t = (unsigned int)__shfl((int)t, 0);
  if (t == NB - 1u) {
    __threadfence();                     // acquire all blocks' part writes
    volatile const float* vp = part;
    double csum = 0.0, lsum = 0.0, nsum = 0.0;
    for (int i = lane; i < NB; i += 64) {
      csum += (double)vp[i * 3 + 0];
      lsum += (double)vp[i * 3 + 1];
      nsum += (double)vp[i * 3 + 2];
    }
#pragma unroll
    for (int off = 32; off; off >>= 1) {
      csum += __shfl_xor(csum, off);
      lsum += __shfl_xor(lsum, off);
      nsum += __shfl_xor(nsum, off);
    }
    if (lane == 0) {
      out[0] = (float)(csum / (nsum * 256.0));  // / sum(point_masks) = 256*sum(n)
      out[1] = (float)(lsum / nsum);            // / sum(line_masks)
    }
  }
}

extern "C" void kernel_launch(void* const* d_in, const int* in_sizes, int n_in,
                              void* d_out, int out_size, void* d_ws, size_t ws_size,
                              hipStream_t stream) {
  const float* pred = (const float*)d_in[0];   // [512,32,256,2] f32
  const float* prob = (const float*)d_in[1];   // [512,32,2] f32
  const float* tgt  = (const float*)d_in[2];   // [512,32,256,2] f32
  const float* lm   = (const float*)d_in[3];   // [512,32] f32
  const int*   clf  = (const int*)d_in[4];     // [512,32] i32

  float* part = (float*)d_ws;                              // [512][3] f32
  unsigned int* counter = (unsigned int*)((char*)d_ws + 8192);  // arrival ticket

  hipMemsetAsync(counter, 0, sizeof(unsigned int), stream);  // stream-ordered, capturable
  fused_kernel<<<NB, 512, 0, stream>>>(pred, prob, tgt, lm, clf, part, counter,
                                       (float*)d_out);
}

// Round 10
// 86.608 us; speedup vs baseline: 1.3419x; 1.3419x over previous
//
#include <hip/hip_runtime.h>
#include <cstdint>
#include <cstddef>

#define NB 512
#define NL 32
#define KD 512    // P*D
#define HKD 256   // k-half per pass

// swizzled float-offset of chunk ch (4 floats) of row `row` in a [32][256] pass buffer.
__device__ __forceinline__ int swz_off(int row, int ch) {
  int csw = (ch & ~15) | ((ch ^ (row >> 1)) & 15);
  return row * HKD + csw * 4;
}

__device__ __forceinline__ float readlane_f(float x, int lane) {
  return __int_as_float(__builtin_amdgcn_readlane(__float_as_int(x), lane));
}
__device__ __forceinline__ int readlane_i(int x, int lane) {
  return __builtin_amdgcn_readlane(x, lane);
}

template<int CTRL, int RM>
__device__ __forceinline__ float dppmin(float x) {
  int m = __builtin_amdgcn_update_dpp(__float_as_int(x), __float_as_int(x), CTRL, RM, 0xf, false);
  return fminf(x, __int_as_float(m));
}
// min over lanes 0..31, broadcast to all lanes via SGPR
__device__ __forceinline__ float wave_min32_bcast(float x) {
  x = dppmin<0xB1, 0xf>(x);   // quad_perm xor1
  x = dppmin<0x4E, 0xf>(x);   // quad_perm xor2
  x = dppmin<0x124, 0xf>(x);  // row_ror:4
  x = dppmin<0x128, 0xf>(x);  // row_ror:8 -> row16 min everywhere
  x = dppmin<0x142, 0xa>(x);  // row_bcast:15 -> lanes 16..31 = min(lanes 0..31)
  return readlane_f(x, 31);
}

// One fused kernel: cost (8-wave k-split) -> LDS reduce -> wave-0 hungarian ->
// last-block finalize. 512 blocks x 512 threads, 64 KB LDS -> 2 blk/CU, 16 waves/CU.
// __launch_bounds__(512, 2): R9 used (512,4) and hipcc applied BLOCKS-per-CU
// semantics -> 8 waves/EU -> 64-VGPR cap -> 546 B/thread scratch spill
// (WRITE_SIZE 143 MB, VGPR_Count 64). (512,2) -> 128-VGPR cap, matching the
// LDS-bound occupancy (2 blocks/CU) with zero spill.
__global__ __launch_bounds__(512, 2)
void fused_kernel(const float* __restrict__ pred,
                  const float* __restrict__ prob,
                  const float* __restrict__ tgt,
                  const float* __restrict__ lmask,
                  const int* __restrict__ clf,
                  float* __restrict__ part,
                  unsigned int* __restrict__ counter,
                  float* __restrict__ out) {
  __shared__ float smem[16384];   // 64 KB: staging; aliased by partials + cost later
  const int b = blockIdx.x;
  const int tid = threadIdx.x;
  float* predH = smem;
  float* tgtH  = smem + 8192;

  const int w = tid >> 6, l = tid & 63;   // 8 waves, each owns a 32-float k-slice/pass
  const int ti = l >> 3, tj = l & 7;      // 8x8 lanes of 4x4 output tiles
  float acc[4][4];
#pragma unroll
  for (int a = 0; a < 4; ++a)
#pragma unroll
    for (int c2 = 0; c2 < 4; ++c2) acc[a][c2] = 0.f;

  for (int hp = 0; hp < 2; ++hp) {
    __syncthreads();
    const size_t base = (size_t)b * (NL * KD) + (size_t)hp * HKD;
#pragma unroll
    for (int it = 0; it < 4; ++it) {
      int chunk = tid + it * 512;          // 0..2047 -> row, chunk-in-row
      int row = chunk >> 6, ch = chunk & 63;
      const float4 pv = *reinterpret_cast<const float4*>(pred + base + (size_t)row * KD + ch * 4);
      const float4 tv = *reinterpret_cast<const float4*>(tgt  + base + (size_t)row * KD + ch * 4);
      int off = swz_off(row, ch);
      *reinterpret_cast<float4*>(predH + off) = pv;
      *reinterpret_cast<float4*>(tgtH  + off) = tv;
    }
    __syncthreads();
#pragma unroll
    for (int c0 = 0; c0 < 8; ++c0) {
      const int c = (w << 3) + c0;         // wave's 8 chunks of this pass
      float4 pr[4], tg[4];
#pragma unroll
      for (int r = 0; r < 4; ++r) {
        pr[r] = *reinterpret_cast<const float4*>(predH + swz_off(4 * ti + r, c));
        tg[r] = *reinterpret_cast<const float4*>(tgtH  + swz_off(4 * tj + r, c));
      }
#pragma unroll
      for (int a = 0; a < 4; ++a)
#pragma unroll
        for (int c2 = 0; c2 < 4; ++c2) {
          float d;
          d = pr[a].x - tg[c2].x; acc[a][c2] += d * d;
          d = pr[a].y - tg[c2].y; acc[a][c2] += d * d;
          d = pr[a].z - tg[c2].z; acc[a][c2] += d * d;
          d = pr[a].w - tg[c2].w; acc[a][c2] += d * d;
        }
    }
  }
  __syncthreads();   // all staging reads done; alias LDS: partials in [0..8192)
#pragma unroll
  for (int a = 0; a < 4; ++a) {
    float4 v = make_float4(acc[a][0], acc[a][1], acc[a][2], acc[a][3]);
    *reinterpret_cast<float4*>(&smem[w * 1024 + (4 * ti + a) * 32 + 4 * tj]) = v;
  }
  __syncthreads();
  {  // reduce 8 k-planes; cost -> smem[8192..9216) (old tgtH start, reads done)
    float2 s = make_float2(0.f, 0.f);
#pragma unroll
    for (int w2 = 0; w2 < 8; ++w2) {
      float2 p = *reinterpret_cast<const float2*>(&smem[w2 * 1024 + 2 * tid]);
      s.x += p.x; s.y += p.y;
    }
    *reinterpret_cast<float2*>(&smem[8192 + 2 * tid]) = s;
  }
  __syncthreads();

  if (tid >= 64) return;            // waves 1-7 exit; wave 0 runs the matching
  const float* cs = smem + 8192;    // cost[32][32]
  const int lane = tid;

  float lm = (lane < 32) ? lmask[b * 32 + lane] : 0.f;
  const int n = __popcll(__ballot(lm > 0.5f));
  float clfpart = 0.f;
  if (lane < 32 && lm > 0.5f) {
    int cc = clf[b * 32 + lane];
    clfpart = -logf(prob[(size_t)(b * 32 + lane) * 2 + cc]);
  }

  const float FINF = 1e30f;
  const bool activecol = (lane < n);
  const int cl = lane & 31;   // lanes 32..63 mirror -> same-addr broadcast (free)

  // Reference-faithful broken JV (minv/way never persisted in the python):
  // each step: fresh argmin over free cols of cost[i0][j]-u[i0]-v[j];
  // "augment" collapses to p[j_final] = ri. The uniform u[i0] doesn't affect
  // the argmin, so the min runs on key = c - v; delta = min(key) - u[i0].
  float u_r = 0.f, v_j = 0.f;
  int p_j = -1;

  for (int ri = 0; ri < n; ++ri) {
    int i0 = ri;
    bool usedc = false;
    bool usedr = (lane == ri);
    float rowv = cs[i0 * 32 + cl];
    while (true) {
      float key = rowv - v_j;                   // reduced cost (sans uniform u0)
      bool act = activecol && !usedc;
      float m = act ? key : FINF;
      float u0 = readlane_f(u_r, i0);           // off the min critical path
      float mn = wave_min32_bcast(m);
      uint64_t tie = __ballot(m == mn);
      int j1 = __ffsll((unsigned long long)tie) - 1;  // numpy first-index tie-break
      int pj1 = readlane_i(p_j, j1);
      int i0n = pj1 < 0 ? 0 : pj1;
      float rowv_n = cs[i0n * 32 + cl];         // speculative next-row read (pre-branch)
      float delta = mn - u0;
      if (usedr) u_r += delta;                  // u[p[used]] += delta
      if (usedc) v_j -= delta;                  // v[used]    -= delta
      if (pj1 < 0) {                            // free column -> p[j1] = ri, done
        if (lane == j1) p_j = ri;
        break;
      }
      usedc = usedc || (lane == j1);
      i0 = pj1;
      usedr = usedr || (lane == i0);
      rowv = rowv_n;
    }
  }

  // column j matched to row p[j] -> contributes cost[p[j]][j]
  int pj = p_j < 0 ? 0 : p_j;
  float a = activecol ? cs[pj * 32 + cl] : 0.f;
#pragma unroll
  for (int off = 32; off; off >>= 1) {
    a += __shfl_xor(a, off);
    clfpart += __shfl_xor(clfpart, off);
  }
  if (lane == 0) {
    part[b * 3 + 0] = a;
    part[b * 3 + 1] = clfpart;
    part[b * 3 + 2] = (float)n;
  }

  // ---- last-block finalize (device-scope release/acquire per G16) ----
  // counter is memset to 0 on the stream before this kernel each call, so the
  // TRUE last arrival (and only it) sees t == NB-1.
  __threadfence();                       // release part[b] writes
  unsigned int t = 0;
  if (lane == 0) t = atomicAdd(counter, 1u);
  t = (unsigned int)__shfl((int)t, 0);
  if (t == NB - 1u) {
    __threadfence();                     // acquire all blocks' part writes
    volatile const float* vp = part;
    double csum = 0.0, lsum = 0.0, nsum = 0.0;
    for (int i = lane; i < NB; i += 64) {
      csum += (double)vp[i * 3 + 0];
      lsum += (double)vp[i * 3 + 1];
      nsum += (double)vp[i * 3 + 2];
    }
#pragma unroll
    for (int off = 32; off; off >>= 1) {
      csum += __shfl_xor(csum, off);
      lsum += __shfl_xor(lsum, off);
      nsum += __shfl_xor(nsum, off);
    }
    if (lane == 0) {
      out[0] = (float)(csum / (nsum * 256.0));  // / sum(point_masks) = 256*sum(n)
      out[1] = (float)(lsum / nsum);            // / sum(line_masks)
    }
  }
}

extern "C" void kernel_launch(void* const* d_in, const int* in_sizes, int n_in,
                              void* d_out, int out_size, void* d_ws, size_t ws_size,
                              hipStream_t stream) {
  const float* pred = (const float*)d_in[0];   // [512,32,256,2] f32
  const float* prob = (const float*)d_in[1];   // [512,32,2] f32
  const float* tgt  = (const float*)d_in[2];   // [512,32,256,2] f32
  const float* lm   = (const float*)d_in[3];   // [512,32] f32
  const int*   clf  = (const int*)d_in[4];     // [512,32] i32

  float* part = (float*)d_ws;                              // [512][3] f32
  unsigned int* counter = (unsigned int*)((char*)d_ws + 8192);  // arrival ticket

  hipMemsetAsync(counter, 0, sizeof(unsigned int), stream);  // stream-ordered, capturable
  fused_kernel<<<NB, 512, 0, stream>>>(pred, prob, tgt, lm, clf, part, counter,
                                       (float*)d_out);
}